// Round 5
// baseline (1259.712 us; speedup 1.0000x reference)
//
#include <hip/hip_runtime.h>
#include <hip/hip_bf16.h>

// ---------------------------------------------------------------------------
// VQ-VAE QNetwork forward, fp32 throughout (VQ argmin must match np fp32).
// Layouts all NCHW-flat. B=1024.
//   h1  [B,32,21,21]   h2 [B,64,10,10]  enc [B,64,8,8]  quant [B,64,8,8]
//   d1  [B,64,10,10]   d2 [B,32,21,21]  hidden [B,512]
// Conv family: block = one image, input staged in LDS, wave = 16 (or 8) oc,
// lane = output pixel; weights wave-uniform (scalar loads).
// VQ: wave = one image, lane = position, q[64] in VGPRs, e wave-uniform.
// ---------------------------------------------------------------------------

#define ENC_SCALE (1.0f/65025.0f)   // (x/255)/255

__global__ __launch_bounds__(256) void zero_k(float* __restrict__ hidden,
                                              float* __restrict__ accum) {
  int t = blockIdx.x * 256 + threadIdx.x;
  if (t < 524288) hidden[t] = 0.f;
  if (t < 8) accum[t] = 0.f;
}

// ---- conv1: [B,4,84,84] -> [B,32,21,21], k4 s4, scale 1/255^2, relu -------
__global__ __launch_bounds__(256) void conv1_k(
    const float* __restrict__ x, const float* __restrict__ w1,
    const float* __restrict__ b1, float* __restrict__ out) {
  int lane = threadIdx.x & 63;
  int wv = __builtin_amdgcn_readfirstlane(threadIdx.x >> 6);
  int oc0 = wv * 8;                        // 4 waves -> 32 oc
  int p = blockIdx.x * 64 + lane;          // 451584 pixels
  int b = p / 441, rem = p % 441;
  int oy = rem / 21, ox = rem % 21;
  const float* xb = x + (long)b * 28224 + (oy * 4) * 84 + ox * 4;
  const float* wp = w1 + oc0 * 64;
  float acc[8];
  #pragma unroll
  for (int c = 0; c < 8; ++c) acc[c] = b1[oc0 + c];
  #pragma unroll 1
  for (int i = 0; i < 4; ++i)
    #pragma unroll
    for (int ky = 0; ky < 4; ++ky)
      #pragma unroll
      for (int kx = 0; kx < 4; ++kx) {
        float v = xb[i * 7056 + ky * 84 + kx] * ENC_SCALE;
        int t = i * 16 + ky * 4 + kx;
        #pragma unroll
        for (int c = 0; c < 8; ++c)
          acc[c] = fmaf(v, wp[c * 64 + t], acc[c]);
      }
  float* ob = out + ((long)b * 32 + oc0) * 441 + rem;
  #pragma unroll
  for (int c = 0; c < 8; ++c) ob[c * 441] = fmaxf(acc[c], 0.f);
}

// ---- conv2: [B,32,21,21] -> [B,64,10,10], k3 s2, relu. Block = image. -----
__global__ __launch_bounds__(256) void conv2_k(
    const float* __restrict__ in, const float* __restrict__ w,
    const float* __restrict__ bias, float* __restrict__ out) {
  __shared__ float in_s[32 * 441];         // 56.4 KB
  int b = blockIdx.x, tid = threadIdx.x;
  const float4* src = (const float4*)(in + (long)b * 14112);
  for (int i = tid; i < 3528; i += 256) *(float4*)&in_s[i * 4] = src[i];
  __syncthreads();
  int lane = tid & 63;
  int wv = __builtin_amdgcn_readfirstlane(tid >> 6);
  int oc0 = wv * 16;
  int pxA = lane;                          // 0..63
  int pxB = 64 + lane; if (pxB > 99) pxB = 99;
  int oyA = pxA / 10, oxA = pxA % 10;
  int oyB = pxB / 10, oxB = pxB % 10;
  float accA[16], accB[16];
  #pragma unroll
  for (int o = 0; o < 16; ++o) { float bv = bias[oc0 + o]; accA[o] = bv; accB[o] = bv; }
  #pragma unroll 2
  for (int ic = 0; ic < 32; ++ic) {
    const float* is = in_s + ic * 441;
    float a[9], bb[9];
    #pragma unroll
    for (int ky = 0; ky < 3; ++ky)
      #pragma unroll
      for (int kx = 0; kx < 3; ++kx) {
        a[ky * 3 + kx]  = is[(2 * oyA + ky) * 21 + 2 * oxA + kx];
        bb[ky * 3 + kx] = is[(2 * oyB + ky) * 21 + 2 * oxB + kx];
      }
    #pragma unroll
    for (int o = 0; o < 16; ++o) {
      const float* wp = w + (long)(oc0 + o) * 288 + ic * 9;
      #pragma unroll
      for (int t = 0; t < 9; ++t) {
        float wt = wp[t];
        accA[o] = fmaf(a[t], wt, accA[o]);
        accB[o] = fmaf(bb[t], wt, accB[o]);
      }
    }
  }
  float* ob = out + ((long)b * 64 + oc0) * 100;
  #pragma unroll
  for (int o = 0; o < 16; ++o) {
    ob[o * 100 + pxA] = fmaxf(accA[o], 0.f);
    if (lane < 36) ob[o * 100 + 64 + lane] = fmaxf(accB[o], 0.f);
  }
}

// ---- conv3: [B,64,10,10] -> [B,64,8,8], k3 s1, relu. Block = image. -------
__global__ __launch_bounds__(256) void conv3_k(
    const float* __restrict__ in, const float* __restrict__ w,
    const float* __restrict__ bias, float* __restrict__ out) {
  __shared__ float in_s[6400];             // 25.6 KB
  int b = blockIdx.x, tid = threadIdx.x;
  const float4* src = (const float4*)(in + (long)b * 6400);
  for (int i = tid; i < 1600; i += 256) *(float4*)&in_s[i * 4] = src[i];
  __syncthreads();
  int lane = tid & 63;
  int wv = __builtin_amdgcn_readfirstlane(tid >> 6);
  int oc0 = wv * 16;
  int oy = lane >> 3, ox = lane & 7;       // 64 px exactly
  float acc[16];
  #pragma unroll
  for (int o = 0; o < 16; ++o) acc[o] = bias[oc0 + o];
  #pragma unroll 2
  for (int ic = 0; ic < 64; ++ic) {
    const float* is = in_s + ic * 100;
    float a[9];
    #pragma unroll
    for (int ky = 0; ky < 3; ++ky)
      #pragma unroll
      for (int kx = 0; kx < 3; ++kx)
        a[ky * 3 + kx] = is[(oy + ky) * 10 + ox + kx];
    #pragma unroll
    for (int o = 0; o < 16; ++o) {
      const float* wp = w + (long)(oc0 + o) * 576 + ic * 9;
      #pragma unroll
      for (int t = 0; t < 9; ++t) acc[o] = fmaf(a[t], wp[t], acc[o]);
    }
  }
  float* ob = out + ((long)b * 64 + oc0) * 64 + lane;
  #pragma unroll
  for (int o = 0; o < 16; ++o) ob[o * 64] = fmaxf(acc[o], 0.f);
}

// ---- VQ: wave = image, lane = position, q in VGPRs, e wave-uniform --------
// Coalesced quant writes (d-major stores, gathered emb reads).
__global__ __launch_bounds__(256) void vq_k(
    const float* __restrict__ enc, const float* __restrict__ emb,
    float* __restrict__ quant, float* __restrict__ vqpart) {
  __shared__ float ee_s[512];
  __shared__ float lsum[4];
  int tid = threadIdx.x;
  // per-block ||e||^2 table (ascending-d order, matches prior passing kernel)
  for (int k = tid; k < 512; k += 256) {
    const float* ep = emb + k * 64;
    float s = 0.f;
    #pragma unroll
    for (int d = 0; d < 64; ++d) s = fmaf(ep[d], ep[d], s);
    ee_s[k] = s;
  }
  __syncthreads();
  int w = tid >> 6, lane = tid & 63;
  int b = blockIdx.x * 4 + w;              // 256 blocks x 4 waves = 1024 images
  const float* qb = enc + ((long)b << 12) + lane;
  float q[64];
  #pragma unroll
  for (int d = 0; d < 64; ++d) q[d] = qb[d << 6];
  float qq = 0.f;
  #pragma unroll
  for (int d = 0; d < 64; ++d) qq = fmaf(q[d], q[d], qq);
  float best = 1e30f; int bk = 0;
  #pragma unroll 4
  for (int k = 0; k < 512; ++k) {
    const float* ep = emb + (k << 6);      // wave-uniform address
    float dot = 0.f;
    #pragma unroll
    for (int d = 0; d < 64; ++d) dot = fmaf(q[d], ep[d], dot);
    float sc = fmaf(-2.f, dot, ee_s[k]);
    if (sc < best) { best = sc; bk = k; }  // strict < keeps lowest index
  }
  // quant[(b*64+d)*64 + lane] = emb[bk*64+d]: coalesced stores, L2-hot gathers
  float* qo = quant + ((long)b << 12) + lane;
  const float* eb = emb + (bk << 6);
  #pragma unroll 8
  for (int d = 0; d < 64; ++d) qo[d << 6] = eb[d];
  float ls = qq + best;
  #pragma unroll
  for (int off = 32; off; off >>= 1) ls += __shfl_down(ls, off);
  if (lane == 0) lsum[w] = ls;
  __syncthreads();
  if (tid == 0) vqpart[blockIdx.x] = lsum[0] + lsum[1] + lsum[2] + lsum[3];
}

// ---- deconv1: [B,64,8,8] -> [B,64,10,10], full-corr k3. Block = image. ----
__global__ __launch_bounds__(256) void dec1_k(
    const float* __restrict__ in, const float* __restrict__ w,
    const float* __restrict__ bias, float* __restrict__ out) {
  __shared__ float in_s[64 * 144];         // 36.9 KB
  int b = blockIdx.x, tid = threadIdx.x;
  for (int i = tid; i < 9216; i += 256) in_s[i] = 0.f;
  __syncthreads();
  const float* src = in + (long)b * 4096;
  for (int i = tid; i < 4096; i += 256) {
    int ic = i >> 6, p = i & 63;
    in_s[ic * 144 + (2 + (p >> 3)) * 12 + 2 + (p & 7)] = src[i];
  }
  __syncthreads();
  int lane = tid & 63;
  int wv = __builtin_amdgcn_readfirstlane(tid >> 6);
  int oc0 = wv * 16;
  int pxA = lane;
  int pxB = 64 + lane; if (pxB > 99) pxB = 99;
  int oyA = pxA / 10, oxA = pxA % 10;
  int oyB = pxB / 10, oxB = pxB % 10;
  float accA[16], accB[16];
  #pragma unroll
  for (int o = 0; o < 16; ++o) { float bv = bias[oc0 + o]; accA[o] = bv; accB[o] = bv; }
  #pragma unroll 2
  for (int ic = 0; ic < 64; ++ic) {
    const float* is = in_s + ic * 144;
    float a[9], bb[9];
    #pragma unroll
    for (int ky = 0; ky < 3; ++ky)
      #pragma unroll
      for (int kx = 0; kx < 3; ++kx) {
        a[ky * 3 + kx]  = is[(oyA + ky) * 12 + oxA + kx];
        bb[ky * 3 + kx] = is[(oyB + ky) * 12 + oxB + kx];
      }
    #pragma unroll
    for (int o = 0; o < 16; ++o) {
      const float* wp = w + (long)(oc0 + o) * 576 + ic * 9;
      #pragma unroll
      for (int t = 0; t < 9; ++t) {
        float wt = wp[t];
        accA[o] = fmaf(a[t], wt, accA[o]);
        accB[o] = fmaf(bb[t], wt, accB[o]);
      }
    }
  }
  float* ob = out + ((long)b * 64 + oc0) * 100;
  #pragma unroll
  for (int o = 0; o < 16; ++o) {
    ob[o * 100 + pxA] = fmaxf(accA[o], 0.f);
    if (lane < 36) ob[o * 100 + 64 + lane] = fmaxf(accB[o], 0.f);
  }
}

// ---- deconv2: [B,64,10,10] -> [B,32,21,21], k3 s2, relu. Block = image. ---
__global__ __launch_bounds__(256) void dec2_k(
    const float* __restrict__ in, const float* __restrict__ w,
    const float* __restrict__ bias, float* __restrict__ out) {
  __shared__ float in_s[64 * 144];         // 36.9 KB
  int b = blockIdx.x, tid = threadIdx.x;
  for (int i = tid; i < 9216; i += 256) in_s[i] = 0.f;
  __syncthreads();
  const float* src = in + (long)b * 6400;
  for (int i = tid; i < 6400; i += 256) {
    int ic = i / 100, p = i % 100;
    in_s[ic * 144 + (p / 10) * 12 + (p % 10)] = src[i];
  }
  __syncthreads();
  int lane = tid & 63;
  int wv = __builtin_amdgcn_readfirstlane(tid >> 6);
  int oc0 = wv * 8;
  float* ob = out + ((long)b * 32 + oc0) * 441;
  float bias8[8];
  #pragma unroll
  for (int o = 0; o < 8; ++o) bias8[o] = bias[oc0 + o];

  #pragma unroll 1
  for (int pp = 0; pp < 2; ++pp) {
    int idx = pp * 64 + lane; bool okl = idx < 121; int ii = okl ? idx : 0;
    int u = ii / 11, v = ii % 11;
    float acc[8];
    #pragma unroll
    for (int o = 0; o < 8; ++o) acc[o] = bias8[o];
    #pragma unroll 2
    for (int ic = 0; ic < 64; ++ic) {
      const float* is = in_s + ic * 144;
      float i00 = is[(u + 1) * 12 + v + 1];
      float i02 = is[(u + 1) * 12 + v];
      float i20 = is[u * 12 + v + 1];
      float i22 = is[u * 12 + v];
      #pragma unroll
      for (int o = 0; o < 8; ++o) {
        const float* wp = w + (long)(oc0 + o) * 576 + ic * 9;
        acc[o] = fmaf(i00, wp[0], acc[o]);
        acc[o] = fmaf(i02, wp[2], acc[o]);
        acc[o] = fmaf(i20, wp[6], acc[o]);
        acc[o] = fmaf(i22, wp[8], acc[o]);
      }
    }
    if (okl) {
      int off = (2 * u) * 21 + 2 * v;
      #pragma unroll
      for (int o = 0; o < 8; ++o) ob[o * 441 + off] = fmaxf(acc[o], 0.f);
    }
  }
  #pragma unroll 1
  for (int pp = 0; pp < 2; ++pp) {
    int idx = pp * 64 + lane; bool okl = idx < 110; int ii = okl ? idx : 0;
    int u = ii / 10, v = ii % 10;
    float acc[8];
    #pragma unroll
    for (int o = 0; o < 8; ++o) acc[o] = bias8[o];
    #pragma unroll 2
    for (int ic = 0; ic < 64; ++ic) {
      const float* is = in_s + ic * 144;
      float i0 = is[(u + 1) * 12 + v + 1];
      float i2 = is[u * 12 + v + 1];
      #pragma unroll
      for (int o = 0; o < 8; ++o) {
        const float* wp = w + (long)(oc0 + o) * 576 + ic * 9;
        acc[o] = fmaf(i0, wp[1], acc[o]);
        acc[o] = fmaf(i2, wp[7], acc[o]);
      }
    }
    if (okl) {
      int off = (2 * u) * 21 + 2 * v + 1;
      #pragma unroll
      for (int o = 0; o < 8; ++o) ob[o * 441 + off] = fmaxf(acc[o], 0.f);
    }
  }
  #pragma unroll 1
  for (int pp = 0; pp < 2; ++pp) {
    int idx = pp * 64 + lane; bool okl = idx < 110; int ii = okl ? idx : 0;
    int u = ii / 11, v = ii % 11;
    float acc[8];
    #pragma unroll
    for (int o = 0; o < 8; ++o) acc[o] = bias8[o];
    #pragma unroll 2
    for (int ic = 0; ic < 64; ++ic) {
      const float* is = in_s + ic * 144;
      float i0 = is[(u + 1) * 12 + v + 1];
      float i2 = is[(u + 1) * 12 + v];
      #pragma unroll
      for (int o = 0; o < 8; ++o) {
        const float* wp = w + (long)(oc0 + o) * 576 + ic * 9;
        acc[o] = fmaf(i0, wp[3], acc[o]);
        acc[o] = fmaf(i2, wp[5], acc[o]);
      }
    }
    if (okl) {
      int off = (2 * u + 1) * 21 + 2 * v;
      #pragma unroll
      for (int o = 0; o < 8; ++o) ob[o * 441 + off] = fmaxf(acc[o], 0.f);
    }
  }
  #pragma unroll 1
  for (int pp = 0; pp < 2; ++pp) {
    int idx = pp * 64 + lane; bool okl = idx < 100; int ii = okl ? idx : 0;
    int u = ii / 10, v = ii % 10;
    float acc[8];
    #pragma unroll
    for (int o = 0; o < 8; ++o) acc[o] = bias8[o];
    #pragma unroll 2
    for (int ic = 0; ic < 64; ++ic) {
      const float* is = in_s + ic * 144;
      float i0 = is[(u + 1) * 12 + v + 1];
      #pragma unroll
      for (int o = 0; o < 8; ++o) {
        const float* wp = w + (long)(oc0 + o) * 576 + ic * 9;
        acc[o] = fmaf(i0, wp[4], acc[o]);
      }
    }
    if (okl) {
      int off = (2 * u + 1) * 21 + 2 * v + 1;
      #pragma unroll
      for (int o = 0; o < 8; ++o) ob[o * 441 + off] = fmaxf(acc[o], 0.f);
    }
  }
}

// ---- deconv3 + sigmoid + rec-loss, 4x4 tile/thread, NO atomics ------------
__global__ __launch_bounds__(256) void dec3_k(
    const float* __restrict__ d2, const float* __restrict__ dw3,
    const float* __restrict__ db3, const float* __restrict__ x,
    float* __restrict__ part) {
  int t = blockIdx.x * 256 + threadIdx.x;      // 451584 tiles = 1764 blocks
  int b = t / 441, r = t % 441;
  int ty = r / 21, tx = r % 21;
  const float* ib = d2 + (long)b * 14112 + ty * 21 + tx;
  float acc[4][4][4];                          // [c][ry][rx]
  #pragma unroll
  for (int c = 0; c < 4; ++c) {
    float bv = db3[c];
    #pragma unroll
    for (int ry = 0; ry < 4; ++ry)
      #pragma unroll
      for (int rx = 0; rx < 4; ++rx) acc[c][ry][rx] = bv;
  }
  #pragma unroll 4
  for (int i = 0; i < 32; ++i) {
    float v = ib[i * 441];
    #pragma unroll
    for (int c = 0; c < 4; ++c) {
      const float* wp = dw3 + (c * 32 + i) * 16;
      #pragma unroll
      for (int ky = 0; ky < 4; ++ky) {
        float4 wv = *(const float4*)(wp + ky * 4);
        int ry = 3 - ky;
        acc[c][ry][3] = fmaf(v, wv.x, acc[c][ry][3]);
        acc[c][ry][2] = fmaf(v, wv.y, acc[c][ry][2]);
        acc[c][ry][1] = fmaf(v, wv.z, acc[c][ry][1]);
        acc[c][ry][0] = fmaf(v, wv.w, acc[c][ry][0]);
      }
    }
  }
  int y0 = ty * 4, x0 = tx * 4;
  const float* xb = x + (long)b * 28224 + y0 * 84 + x0;
  float ls = 0.f;
  #pragma unroll
  for (int c = 0; c < 4; ++c)
    #pragma unroll
    for (int ry = 0; ry < 4; ++ry) {
      float4 xv = *(const float4*)(xb + c * 7056 + ry * 84);
      float xs[4] = {xv.x, xv.y, xv.z, xv.w};
      #pragma unroll
      for (int rx = 0; rx < 4; ++rx) {
        float dec = 1.f / (1.f + __expf(-acc[c][ry][rx]));
        float df = dec - xs[rx] * (1.f / 255.f);
        ls = fmaf(df, df, ls);
      }
    }
  #pragma unroll
  for (int off = 32; off; off >>= 1) ls += __shfl_down(ls, off);
  __shared__ float r4[4];
  if ((threadIdx.x & 63) == 0) r4[threadIdx.x >> 6] = ls;
  __syncthreads();
  if (threadIdx.x == 0) part[blockIdx.x] = r4[0] + r4[1] + r4[2] + r4[3];
}

// ---- reduce: sum dec3 partials (1764) and vq partials (256) into accum ----
__global__ __launch_bounds__(256) void reduce_k(
    const float* __restrict__ dec3part, const float* __restrict__ vqpart,
    float* __restrict__ accum) {
  int tid = threadIdx.x;
  float s0 = 0.f, s1 = 0.f;
  for (int i = tid; i < 1764; i += 256) s0 += dec3part[i];
  if (tid < 256) s1 = vqpart[tid];
  #pragma unroll
  for (int off = 32; off; off >>= 1) {
    s0 += __shfl_down(s0, off);
    s1 += __shfl_down(s1, off);
  }
  __shared__ float a0[4], a1[4];
  int lane = tid & 63, w = tid >> 6;
  if (lane == 0) { a0[w] = s0; a1[w] = s1; }
  __syncthreads();
  if (tid == 0) {
    accum[0] = a0[0] + a0[1] + a0[2] + a0[3];
    accum[1] = a1[0] + a1[1] + a1[2] + a1[3];
  }
}

// ---- FC1: hidden += quant_flat @ lw1 (k-split 4, 16-batch regs, atomics) --
__global__ __launch_bounds__(256) void fc1_k(
    const float* __restrict__ quant, const float* __restrict__ lw1,
    float* __restrict__ hidden) {
  int n = (blockIdx.x & 1) * 256 + threadIdx.x;
  int bg = (blockIdx.x >> 1) & 63;
  int ks = blockIdx.x >> 7;                // 0..3
  int b0 = bg * 16;
  const float* q0 = quant + (long)b0 * 4096 + ks * 1024;
  const float* w0 = lw1 + (long)ks * 1024 * 512 + n;
  float acc[16] = {};
  #pragma unroll 4
  for (int k = 0; k < 1024; ++k) {
    float wvv = w0[(long)k * 512];
    #pragma unroll
    for (int bb = 0; bb < 16; ++bb)
      acc[bb] = fmaf(q0[bb * 4096 + k], wvv, acc[bb]);
  }
  #pragma unroll
  for (int bb = 0; bb < 16; ++bb)
    atomicAdd(&hidden[(b0 + bb) * 512 + n], acc[bb]);
}

// ---- FC2: q_values = relu(hidden + lb1) @ lw2 + lb2; write losses ---------
__global__ __launch_bounds__(256) void fc2_k(
    const float* __restrict__ hidden, const float* __restrict__ lb1,
    const float* __restrict__ lw2, const float* __restrict__ lb2,
    const float* __restrict__ accum, float* __restrict__ out) {
  int t = blockIdx.x * 256 + threadIdx.x;  // 18432
  int b = t / 18, a = t % 18;
  const float* h = hidden + b * 512;
  float acc = lb2[a];
  #pragma unroll 4
  for (int n = 0; n < 512; ++n) {
    float hv = fmaxf(h[n] + lb1[n], 0.f);
    acc = fmaf(hv, lw2[n * 18 + a], acc);
  }
  out[t] = acc;
  if (t == 0) {
    out[18432] = accum[0] * (1.f / 28901376.f);          // /(1024*4*84*84)
    out[18433] = 1.25f * accum[1] * (1.f / 4194304.f);   // /(65536*64)
  }
}

extern "C" void kernel_launch(void* const* d_in, const int* in_sizes, int n_in,
                              void* d_out, int out_size, void* d_ws, size_t ws_size,
                              hipStream_t stream) {
  const float* x   = (const float*)d_in[0];
  const float* w1  = (const float*)d_in[1];
  const float* b1  = (const float*)d_in[2];
  const float* w2  = (const float*)d_in[3];
  const float* b2  = (const float*)d_in[4];
  const float* w3  = (const float*)d_in[5];
  const float* b3  = (const float*)d_in[6];
  const float* emb = (const float*)d_in[7];
  const float* dw1 = (const float*)d_in[8];
  const float* db1 = (const float*)d_in[9];
  const float* dw2 = (const float*)d_in[10];
  const float* db2 = (const float*)d_in[11];
  const float* dw3 = (const float*)d_in[12];
  const float* db3 = (const float*)d_in[13];
  const float* lw1 = (const float*)d_in[14];
  const float* lb1 = (const float*)d_in[15];
  const float* lw2 = (const float*)d_in[16];
  const float* lb2 = (const float*)d_in[17];

  float* ws = (float*)d_ws;
  float* h1     = ws;                    // 14450688 floats [B,32,21,21]
  float* h2     = ws + 14450688;         //  6553600 floats [B,64,10,10]
  float* enc    = ws + 21004288;         //  4194304 floats [B,64,8,8]
  float* quant  = ws + 25198592;         //  4194304 floats [B,64,8,8]
  float* d1     = h2;                    // reuse (h2 dead after conv3)
  float* d2b    = h1;                    // reuse (h1 dead after conv2)
  float* hidden = ws + 29392896;         //   524288 floats [B,512]
  float* accum  = ws + 29917184;         // [0]=rec sum, [1]=quant sum
  float* d3part = ws + 29917192;         // 1764 floats
  float* vqpart = ws + 29918956;         // 256 floats used
  float* outp   = (float*)d_out;

  zero_k<<<2048, 256, 0, stream>>>(hidden, accum);
  conv1_k<<<dim3(7056, 1), 256, 0, stream>>>(x, w1, b1, h1);
  conv2_k<<<1024, 256, 0, stream>>>(h1, w2, b2, h2);
  conv3_k<<<1024, 256, 0, stream>>>(h2, w3, b3, enc);
  vq_k<<<256, 256, 0, stream>>>(enc, emb, quant, vqpart);
  dec1_k<<<1024, 256, 0, stream>>>(quant, dw1, db1, d1);
  dec2_k<<<1024, 256, 0, stream>>>(d1, dw2, db2, d2b);
  dec3_k<<<1764, 256, 0, stream>>>(d2b, dw3, db3, x, d3part);
  reduce_k<<<1, 256, 0, stream>>>(d3part, vqpart, accum);
  fc1_k<<<512, 256, 0, stream>>>(quant, lw1, hidden);
  fc2_k<<<72, 256, 0, stream>>>(hidden, lb1, lw2, lb2, accum, outp);
}

// Round 6
// 1106.580 us; speedup vs baseline: 1.1384x; 1.1384x over previous
//
#include <hip/hip_runtime.h>
#include <hip/hip_bf16.h>

// ---------------------------------------------------------------------------
// VQ-VAE QNetwork forward, fp32 throughout (VQ argmin must match np fp32).
// Layouts all NCHW-flat. B=1024.
//   h1  [B,32,21,21]   h2 [B,64,10,10]  enc [B,64,8,8]  quant [B,64,8,8]
//   d1  [B,64,10,10]   d2 [B,32,21,21]  hidden [B,512]
// Conv family: block = one image, input staged in LDS, wave = 16 (or 8) oc,
// lane = output pixel; weights wave-uniform (scalar loads).
// VQ: block = one image, lane = position, q[64] in VGPRs, wave = 128-code
// chunk (uniform e addresses -> s_load), cross-wave argmin combine in LDS.
// ---------------------------------------------------------------------------

#define ENC_SCALE (1.0f/65025.0f)   // (x/255)/255

__global__ __launch_bounds__(256) void zero_k(float* __restrict__ hidden,
                                              float* __restrict__ accum) {
  int t = blockIdx.x * 256 + threadIdx.x;
  if (t < 524288) hidden[t] = 0.f;
  if (t < 8) accum[t] = 0.f;
}

// ---- conv1: [B,4,84,84] -> [B,32,21,21], k4 s4, scale 1/255^2, relu -------
__global__ __launch_bounds__(256) void conv1_k(
    const float* __restrict__ x, const float* __restrict__ w1,
    const float* __restrict__ b1, float* __restrict__ out) {
  int lane = threadIdx.x & 63;
  int wv = __builtin_amdgcn_readfirstlane(threadIdx.x >> 6);
  int oc0 = wv * 8;                        // 4 waves -> 32 oc
  int p = blockIdx.x * 64 + lane;          // 451584 pixels
  int b = p / 441, rem = p % 441;
  int oy = rem / 21, ox = rem % 21;
  const float* xb = x + (long)b * 28224 + (oy * 4) * 84 + ox * 4;
  const float* wp = w1 + oc0 * 64;
  float acc[8];
  #pragma unroll
  for (int c = 0; c < 8; ++c) acc[c] = b1[oc0 + c];
  #pragma unroll 1
  for (int i = 0; i < 4; ++i)
    #pragma unroll
    for (int ky = 0; ky < 4; ++ky)
      #pragma unroll
      for (int kx = 0; kx < 4; ++kx) {
        float v = xb[i * 7056 + ky * 84 + kx] * ENC_SCALE;
        int t = i * 16 + ky * 4 + kx;
        #pragma unroll
        for (int c = 0; c < 8; ++c)
          acc[c] = fmaf(v, wp[c * 64 + t], acc[c]);
      }
  float* ob = out + ((long)b * 32 + oc0) * 441 + rem;
  #pragma unroll
  for (int c = 0; c < 8; ++c) ob[c * 441] = fmaxf(acc[c], 0.f);
}

// ---- conv2: [B,32,21,21] -> [B,64,10,10], k3 s2, relu. Block = image. -----
__global__ __launch_bounds__(256) void conv2_k(
    const float* __restrict__ in, const float* __restrict__ w,
    const float* __restrict__ bias, float* __restrict__ out) {
  __shared__ float in_s[32 * 441];         // 56.4 KB
  int b = blockIdx.x, tid = threadIdx.x;
  const float4* src = (const float4*)(in + (long)b * 14112);
  for (int i = tid; i < 3528; i += 256) *(float4*)&in_s[i * 4] = src[i];
  __syncthreads();
  int lane = tid & 63;
  int wv = __builtin_amdgcn_readfirstlane(tid >> 6);
  int oc0 = wv * 16;
  int pxA = lane;                          // 0..63
  int pxB = 64 + lane; if (pxB > 99) pxB = 99;
  int oyA = pxA / 10, oxA = pxA % 10;
  int oyB = pxB / 10, oxB = pxB % 10;
  float accA[16], accB[16];
  #pragma unroll
  for (int o = 0; o < 16; ++o) { float bv = bias[oc0 + o]; accA[o] = bv; accB[o] = bv; }
  #pragma unroll 2
  for (int ic = 0; ic < 32; ++ic) {
    const float* is = in_s + ic * 441;
    float a[9], bb[9];
    #pragma unroll
    for (int ky = 0; ky < 3; ++ky)
      #pragma unroll
      for (int kx = 0; kx < 3; ++kx) {
        a[ky * 3 + kx]  = is[(2 * oyA + ky) * 21 + 2 * oxA + kx];
        bb[ky * 3 + kx] = is[(2 * oyB + ky) * 21 + 2 * oxB + kx];
      }
    #pragma unroll
    for (int o = 0; o < 16; ++o) {
      const float* wp = w + (long)(oc0 + o) * 288 + ic * 9;
      #pragma unroll
      for (int t = 0; t < 9; ++t) {
        float wt = wp[t];
        accA[o] = fmaf(a[t], wt, accA[o]);
        accB[o] = fmaf(bb[t], wt, accB[o]);
      }
    }
  }
  float* ob = out + ((long)b * 64 + oc0) * 100;
  #pragma unroll
  for (int o = 0; o < 16; ++o) {
    ob[o * 100 + pxA] = fmaxf(accA[o], 0.f);
    if (lane < 36) ob[o * 100 + 64 + lane] = fmaxf(accB[o], 0.f);
  }
}

// ---- conv3: [B,64,10,10] -> [B,64,8,8], k3 s1, relu. Block = image. -------
__global__ __launch_bounds__(256) void conv3_k(
    const float* __restrict__ in, const float* __restrict__ w,
    const float* __restrict__ bias, float* __restrict__ out) {
  __shared__ float in_s[6400];             // 25.6 KB
  int b = blockIdx.x, tid = threadIdx.x;
  const float4* src = (const float4*)(in + (long)b * 6400);
  for (int i = tid; i < 1600; i += 256) *(float4*)&in_s[i * 4] = src[i];
  __syncthreads();
  int lane = tid & 63;
  int wv = __builtin_amdgcn_readfirstlane(tid >> 6);
  int oc0 = wv * 16;
  int oy = lane >> 3, ox = lane & 7;       // 64 px exactly
  float acc[16];
  #pragma unroll
  for (int o = 0; o < 16; ++o) acc[o] = bias[oc0 + o];
  #pragma unroll 2
  for (int ic = 0; ic < 64; ++ic) {
    const float* is = in_s + ic * 100;
    float a[9];
    #pragma unroll
    for (int ky = 0; ky < 3; ++ky)
      #pragma unroll
      for (int kx = 0; kx < 3; ++kx)
        a[ky * 3 + kx] = is[(oy + ky) * 10 + ox + kx];
    #pragma unroll
    for (int o = 0; o < 16; ++o) {
      const float* wp = w + (long)(oc0 + o) * 576 + ic * 9;
      #pragma unroll
      for (int t = 0; t < 9; ++t) acc[o] = fmaf(a[t], wp[t], acc[o]);
    }
  }
  float* ob = out + ((long)b * 64 + oc0) * 64 + lane;
  #pragma unroll
  for (int o = 0; o < 16; ++o) ob[o * 64] = fmaxf(acc[o], 0.f);
}

// ---- VQ: block = image, lane = position, wave = 128-code chunk ------------
// Same dot order / score formula / tie-break as the passing r5 kernel.
__global__ __launch_bounds__(256) void vq_k(
    const float* __restrict__ enc, const float* __restrict__ emb,
    float* __restrict__ quant, float* __restrict__ vqpart) {
  __shared__ float ee_s[512];
  __shared__ float best_s[4][64];
  __shared__ int   bk_s[4][64];
  int tid = threadIdx.x;
  int w = __builtin_amdgcn_readfirstlane(tid >> 6);
  int lane = tid & 63;
  int b = blockIdx.x;
  // ||e||^2 (ascending d, 2 codes/thread)
  for (int k = tid; k < 512; k += 256) {
    const float* ep = emb + k * 64;
    float s = 0.f;
    #pragma unroll
    for (int d = 0; d < 64; ++d) s = fmaf(ep[d], ep[d], s);
    ee_s[k] = s;
  }
  // q[64] per lane (pos = lane), coalesced stride-64 loads
  const float* qb = enc + ((long)b << 12) + lane;
  float q[64];
  #pragma unroll
  for (int d = 0; d < 64; ++d) q[d] = qb[d << 6];
  __syncthreads();
  float best = 1e30f; int bk = 0;
  int k0 = w * 128;
  #pragma unroll 2
  for (int kk = 0; kk < 128; ++kk) {
    int k = k0 + kk;
    const float* ep = emb + (k << 6);      // wave-uniform -> scalar loads
    float dot = 0.f;
    #pragma unroll
    for (int d = 0; d < 64; ++d) dot = fmaf(q[d], ep[d], dot);
    float sc = fmaf(-2.f, dot, ee_s[k]);
    if (sc < best) { best = sc; bk = k; }  // strict < keeps lowest k in chunk
  }
  best_s[w][lane] = best; bk_s[w][lane] = bk;
  __syncthreads();
  // lexicographic (best, k) min across waves, wave-0-first => lowest index
  float cb = best_s[0][lane]; int ck = bk_s[0][lane];
  #pragma unroll
  for (int j = 1; j < 4; ++j) {
    float ob = best_s[j][lane]; int ok = bk_s[j][lane];
    if (ob < cb || (ob == cb && ok < ck)) { cb = ob; ck = ok; }
  }
  // quant[(b*64+d)*64+lane] = emb[ck*64+d]; wave w writes its d-slice
  float* qo = quant + ((long)b << 12) + lane;
  #pragma unroll
  for (int j = 0; j < 16; ++j) {
    int d = w * 16 + j;
    qo[d << 6] = emb[ck * 64 + d];
  }
  if (w == 0) {
    float qq = 0.f;
    #pragma unroll
    for (int d = 0; d < 64; ++d) qq = fmaf(q[d], q[d], qq);
    float ls = qq + cb;
    #pragma unroll
    for (int off = 32; off; off >>= 1) ls += __shfl_down(ls, off);
    if (lane == 0) vqpart[b] = ls;
  }
}

// ---- deconv1: [B,64,8,8] -> [B,64,10,10], full-corr k3. Block = image. ----
__global__ __launch_bounds__(256) void dec1_k(
    const float* __restrict__ in, const float* __restrict__ w,
    const float* __restrict__ bias, float* __restrict__ out) {
  __shared__ float in_s[64 * 144];         // 36.9 KB
  int b = blockIdx.x, tid = threadIdx.x;
  for (int i = tid; i < 9216; i += 256) in_s[i] = 0.f;
  __syncthreads();
  const float* src = in + (long)b * 4096;
  for (int i = tid; i < 4096; i += 256) {
    int ic = i >> 6, p = i & 63;
    in_s[ic * 144 + (2 + (p >> 3)) * 12 + 2 + (p & 7)] = src[i];
  }
  __syncthreads();
  int lane = tid & 63;
  int wv = __builtin_amdgcn_readfirstlane(tid >> 6);
  int oc0 = wv * 16;
  int pxA = lane;
  int pxB = 64 + lane; if (pxB > 99) pxB = 99;
  int oyA = pxA / 10, oxA = pxA % 10;
  int oyB = pxB / 10, oxB = pxB % 10;
  float accA[16], accB[16];
  #pragma unroll
  for (int o = 0; o < 16; ++o) { float bv = bias[oc0 + o]; accA[o] = bv; accB[o] = bv; }
  #pragma unroll 2
  for (int ic = 0; ic < 64; ++ic) {
    const float* is = in_s + ic * 144;
    float a[9], bb[9];
    #pragma unroll
    for (int ky = 0; ky < 3; ++ky)
      #pragma unroll
      for (int kx = 0; kx < 3; ++kx) {
        a[ky * 3 + kx]  = is[(oyA + ky) * 12 + oxA + kx];
        bb[ky * 3 + kx] = is[(oyB + ky) * 12 + oxB + kx];
      }
    #pragma unroll
    for (int o = 0; o < 16; ++o) {
      const float* wp = w + (long)(oc0 + o) * 576 + ic * 9;
      #pragma unroll
      for (int t = 0; t < 9; ++t) {
        float wt = wp[t];
        accA[o] = fmaf(a[t], wt, accA[o]);
        accB[o] = fmaf(bb[t], wt, accB[o]);
      }
    }
  }
  float* ob = out + ((long)b * 64 + oc0) * 100;
  #pragma unroll
  for (int o = 0; o < 16; ++o) {
    ob[o * 100 + pxA] = fmaxf(accA[o], 0.f);
    if (lane < 36) ob[o * 100 + 64 + lane] = fmaxf(accB[o], 0.f);
  }
}

// ---- deconv2: [B,64,10,10] -> [B,32,21,21], k3 s2, relu. Block = image. ---
__global__ __launch_bounds__(256) void dec2_k(
    const float* __restrict__ in, const float* __restrict__ w,
    const float* __restrict__ bias, float* __restrict__ out) {
  __shared__ float in_s[64 * 144];         // 36.9 KB
  int b = blockIdx.x, tid = threadIdx.x;
  for (int i = tid; i < 9216; i += 256) in_s[i] = 0.f;
  __syncthreads();
  const float* src = in + (long)b * 6400;
  for (int i = tid; i < 6400; i += 256) {
    int ic = i / 100, p = i % 100;
    in_s[ic * 144 + (p / 10) * 12 + (p % 10)] = src[i];
  }
  __syncthreads();
  int lane = tid & 63;
  int wv = __builtin_amdgcn_readfirstlane(tid >> 6);
  int oc0 = wv * 8;
  float* ob = out + ((long)b * 32 + oc0) * 441;
  float bias8[8];
  #pragma unroll
  for (int o = 0; o < 8; ++o) bias8[o] = bias[oc0 + o];

  #pragma unroll 1
  for (int pp = 0; pp < 2; ++pp) {
    int idx = pp * 64 + lane; bool okl = idx < 121; int ii = okl ? idx : 0;
    int u = ii / 11, v = ii % 11;
    float acc[8];
    #pragma unroll
    for (int o = 0; o < 8; ++o) acc[o] = bias8[o];
    #pragma unroll 2
    for (int ic = 0; ic < 64; ++ic) {
      const float* is = in_s + ic * 144;
      float i00 = is[(u + 1) * 12 + v + 1];
      float i02 = is[(u + 1) * 12 + v];
      float i20 = is[u * 12 + v + 1];
      float i22 = is[u * 12 + v];
      #pragma unroll
      for (int o = 0; o < 8; ++o) {
        const float* wp = w + (long)(oc0 + o) * 576 + ic * 9;
        acc[o] = fmaf(i00, wp[0], acc[o]);
        acc[o] = fmaf(i02, wp[2], acc[o]);
        acc[o] = fmaf(i20, wp[6], acc[o]);
        acc[o] = fmaf(i22, wp[8], acc[o]);
      }
    }
    if (okl) {
      int off = (2 * u) * 21 + 2 * v;
      #pragma unroll
      for (int o = 0; o < 8; ++o) ob[o * 441 + off] = fmaxf(acc[o], 0.f);
    }
  }
  #pragma unroll 1
  for (int pp = 0; pp < 2; ++pp) {
    int idx = pp * 64 + lane; bool okl = idx < 110; int ii = okl ? idx : 0;
    int u = ii / 10, v = ii % 10;
    float acc[8];
    #pragma unroll
    for (int o = 0; o < 8; ++o) acc[o] = bias8[o];
    #pragma unroll 2
    for (int ic = 0; ic < 64; ++ic) {
      const float* is = in_s + ic * 144;
      float i0 = is[(u + 1) * 12 + v + 1];
      float i2 = is[u * 12 + v + 1];
      #pragma unroll
      for (int o = 0; o < 8; ++o) {
        const float* wp = w + (long)(oc0 + o) * 576 + ic * 9;
        acc[o] = fmaf(i0, wp[1], acc[o]);
        acc[o] = fmaf(i2, wp[7], acc[o]);
      }
    }
    if (okl) {
      int off = (2 * u) * 21 + 2 * v + 1;
      #pragma unroll
      for (int o = 0; o < 8; ++o) ob[o * 441 + off] = fmaxf(acc[o], 0.f);
    }
  }
  #pragma unroll 1
  for (int pp = 0; pp < 2; ++pp) {
    int idx = pp * 64 + lane; bool okl = idx < 110; int ii = okl ? idx : 0;
    int u = ii / 11, v = ii % 11;
    float acc[8];
    #pragma unroll
    for (int o = 0; o < 8; ++o) acc[o] = bias8[o];
    #pragma unroll 2
    for (int ic = 0; ic < 64; ++ic) {
      const float* is = in_s + ic * 144;
      float i0 = is[(u + 1) * 12 + v + 1];
      float i2 = is[(u + 1) * 12 + v];
      #pragma unroll
      for (int o = 0; o < 8; ++o) {
        const float* wp = w + (long)(oc0 + o) * 576 + ic * 9;
        acc[o] = fmaf(i0, wp[3], acc[o]);
        acc[o] = fmaf(i2, wp[5], acc[o]);
      }
    }
    if (okl) {
      int off = (2 * u + 1) * 21 + 2 * v;
      #pragma unroll
      for (int o = 0; o < 8; ++o) ob[o * 441 + off] = fmaxf(acc[o], 0.f);
    }
  }
  #pragma unroll 1
  for (int pp = 0; pp < 2; ++pp) {
    int idx = pp * 64 + lane; bool okl = idx < 100; int ii = okl ? idx : 0;
    int u = ii / 10, v = ii % 10;
    float acc[8];
    #pragma unroll
    for (int o = 0; o < 8; ++o) acc[o] = bias8[o];
    #pragma unroll 2
    for (int ic = 0; ic < 64; ++ic) {
      const float* is = in_s + ic * 144;
      float i0 = is[(u + 1) * 12 + v + 1];
      #pragma unroll
      for (int o = 0; o < 8; ++o) {
        const float* wp = w + (long)(oc0 + o) * 576 + ic * 9;
        acc[o] = fmaf(i0, wp[4], acc[o]);
      }
    }
    if (okl) {
      int off = (2 * u + 1) * 21 + 2 * v + 1;
      #pragma unroll
      for (int o = 0; o < 8; ++o) ob[o * 441 + off] = fmaxf(acc[o], 0.f);
    }
  }
}

// ---- deconv3 + sigmoid + rec-loss, 4x4 tile/thread, NO atomics ------------
__global__ __launch_bounds__(256) void dec3_k(
    const float* __restrict__ d2, const float* __restrict__ dw3,
    const float* __restrict__ db3, const float* __restrict__ x,
    float* __restrict__ part) {
  int t = blockIdx.x * 256 + threadIdx.x;      // 451584 tiles = 1764 blocks
  int b = t / 441, r = t % 441;
  int ty = r / 21, tx = r % 21;
  const float* ib = d2 + (long)b * 14112 + ty * 21 + tx;
  float acc[4][4][4];                          // [c][ry][rx]
  #pragma unroll
  for (int c = 0; c < 4; ++c) {
    float bv = db3[c];
    #pragma unroll
    for (int ry = 0; ry < 4; ++ry)
      #pragma unroll
      for (int rx = 0; rx < 4; ++rx) acc[c][ry][rx] = bv;
  }
  #pragma unroll 4
  for (int i = 0; i < 32; ++i) {
    float v = ib[i * 441];
    #pragma unroll
    for (int c = 0; c < 4; ++c) {
      const float* wp = dw3 + (c * 32 + i) * 16;
      #pragma unroll
      for (int ky = 0; ky < 4; ++ky) {
        float4 wv = *(const float4*)(wp + ky * 4);
        int ry = 3 - ky;
        acc[c][ry][3] = fmaf(v, wv.x, acc[c][ry][3]);
        acc[c][ry][2] = fmaf(v, wv.y, acc[c][ry][2]);
        acc[c][ry][1] = fmaf(v, wv.z, acc[c][ry][1]);
        acc[c][ry][0] = fmaf(v, wv.w, acc[c][ry][0]);
      }
    }
  }
  int y0 = ty * 4, x0 = tx * 4;
  const float* xb = x + (long)b * 28224 + y0 * 84 + x0;
  float ls = 0.f;
  #pragma unroll
  for (int c = 0; c < 4; ++c)
    #pragma unroll
    for (int ry = 0; ry < 4; ++ry) {
      float4 xv = *(const float4*)(xb + c * 7056 + ry * 84);
      float xs[4] = {xv.x, xv.y, xv.z, xv.w};
      #pragma unroll
      for (int rx = 0; rx < 4; ++rx) {
        float dec = 1.f / (1.f + __expf(-acc[c][ry][rx]));
        float df = dec - xs[rx] * (1.f / 255.f);
        ls = fmaf(df, df, ls);
      }
    }
  #pragma unroll
  for (int off = 32; off; off >>= 1) ls += __shfl_down(ls, off);
  __shared__ float r4[4];
  if ((threadIdx.x & 63) == 0) r4[threadIdx.x >> 6] = ls;
  __syncthreads();
  if (threadIdx.x == 0) part[blockIdx.x] = r4[0] + r4[1] + r4[2] + r4[3];
}

// ---- reduce: sum dec3 partials (1764) and vq partials (1024) into accum ---
__global__ __launch_bounds__(256) void reduce_k(
    const float* __restrict__ dec3part, const float* __restrict__ vqpart,
    float* __restrict__ accum) {
  int tid = threadIdx.x;
  float s0 = 0.f, s1 = 0.f;
  for (int i = tid; i < 1764; i += 256) s0 += dec3part[i];
  for (int i = tid; i < 1024; i += 256) s1 += vqpart[i];
  #pragma unroll
  for (int off = 32; off; off >>= 1) {
    s0 += __shfl_down(s0, off);
    s1 += __shfl_down(s1, off);
  }
  __shared__ float a0[4], a1[4];
  int lane = tid & 63, w = tid >> 6;
  if (lane == 0) { a0[w] = s0; a1[w] = s1; }
  __syncthreads();
  if (tid == 0) {
    accum[0] = a0[0] + a0[1] + a0[2] + a0[3];
    accum[1] = a1[0] + a1[1] + a1[2] + a1[3];
  }
}

// ---- FC1: hidden += quant_flat @ lw1 (k-split 4, 16-batch regs, atomics) --
__global__ __launch_bounds__(256) void fc1_k(
    const float* __restrict__ quant, const float* __restrict__ lw1,
    float* __restrict__ hidden) {
  int n = (blockIdx.x & 1) * 256 + threadIdx.x;
  int bg = (blockIdx.x >> 1) & 63;
  int ks = blockIdx.x >> 7;                // 0..3
  int b0 = bg * 16;
  const float* q0 = quant + (long)b0 * 4096 + ks * 1024;
  const float* w0 = lw1 + (long)ks * 1024 * 512 + n;
  float acc[16] = {};
  #pragma unroll 4
  for (int k = 0; k < 1024; ++k) {
    float wvv = w0[(long)k * 512];
    #pragma unroll
    for (int bb = 0; bb < 16; ++bb)
      acc[bb] = fmaf(q0[bb * 4096 + k], wvv, acc[bb]);
  }
  #pragma unroll
  for (int bb = 0; bb < 16; ++bb)
    atomicAdd(&hidden[(b0 + bb) * 512 + n], acc[bb]);
}

// ---- FC2: q_values = relu(hidden + lb1) @ lw2 + lb2; write losses ---------
__global__ __launch_bounds__(256) void fc2_k(
    const float* __restrict__ hidden, const float* __restrict__ lb1,
    const float* __restrict__ lw2, const float* __restrict__ lb2,
    const float* __restrict__ accum, float* __restrict__ out) {
  int t = blockIdx.x * 256 + threadIdx.x;  // 18432
  int b = t / 18, a = t % 18;
  const float* h = hidden + b * 512;
  float acc = lb2[a];
  #pragma unroll 4
  for (int n = 0; n < 512; ++n) {
    float hv = fmaxf(h[n] + lb1[n], 0.f);
    acc = fmaf(hv, lw2[n * 18 + a], acc);
  }
  out[t] = acc;
  if (t == 0) {
    out[18432] = accum[0] * (1.f / 28901376.f);          // /(1024*4*84*84)
    out[18433] = 1.25f * accum[1] * (1.f / 4194304.f);   // /(65536*64)
  }
}

extern "C" void kernel_launch(void* const* d_in, const int* in_sizes, int n_in,
                              void* d_out, int out_size, void* d_ws, size_t ws_size,
                              hipStream_t stream) {
  const float* x   = (const float*)d_in[0];
  const float* w1  = (const float*)d_in[1];
  const float* b1  = (const float*)d_in[2];
  const float* w2  = (const float*)d_in[3];
  const float* b2  = (const float*)d_in[4];
  const float* w3  = (const float*)d_in[5];
  const float* b3  = (const float*)d_in[6];
  const float* emb = (const float*)d_in[7];
  const float* dw1 = (const float*)d_in[8];
  const float* db1 = (const float*)d_in[9];
  const float* dw2 = (const float*)d_in[10];
  const float* db2 = (const float*)d_in[11];
  const float* dw3 = (const float*)d_in[12];
  const float* db3 = (const float*)d_in[13];
  const float* lw1 = (const float*)d_in[14];
  const float* lb1 = (const float*)d_in[15];
  const float* lw2 = (const float*)d_in[16];
  const float* lb2 = (const float*)d_in[17];

  float* ws = (float*)d_ws;
  float* h1     = ws;                    // 14450688 floats [B,32,21,21]
  float* h2     = ws + 14450688;         //  6553600 floats [B,64,10,10]
  float* enc    = ws + 21004288;         //  4194304 floats [B,64,8,8]
  float* quant  = ws + 25198592;         //  4194304 floats [B,64,8,8]
  float* d1     = h2;                    // reuse (h2 dead after conv3)
  float* d2b    = h1;                    // reuse (h1 dead after conv2)
  float* hidden = ws + 29392896;         //   524288 floats [B,512]
  float* accum  = ws + 29917184;         // [0]=rec sum, [1]=quant sum
  float* d3part = ws + 29917192;         // 1764 floats
  float* vqpart = ws + 29918956;         // 1024 floats
  float* outp   = (float*)d_out;

  zero_k<<<2048, 256, 0, stream>>>(hidden, accum);
  conv1_k<<<dim3(7056, 1), 256, 0, stream>>>(x, w1, b1, h1);
  conv2_k<<<1024, 256, 0, stream>>>(h1, w2, b2, h2);
  conv3_k<<<1024, 256, 0, stream>>>(h2, w3, b3, enc);
  vq_k<<<1024, 256, 0, stream>>>(enc, emb, quant, vqpart);
  dec1_k<<<1024, 256, 0, stream>>>(quant, dw1, db1, d1);
  dec2_k<<<1024, 256, 0, stream>>>(d1, dw2, db2, d2b);
  dec3_k<<<1764, 256, 0, stream>>>(d2b, dw3, db3, x, d3part);
  reduce_k<<<1, 256, 0, stream>>>(d3part, vqpart, accum);
  fc1_k<<<512, 256, 0, stream>>>(quant, lw1, hidden);
  fc2_k<<<72, 256, 0, stream>>>(hidden, lb1, lw2, lb2, accum, outp);
}